// Round 2
// baseline (536.153 us; speedup 1.0000x reference)
//
#include <hip/hip_runtime.h>
#include <cstdint>

namespace {
constexpr int B = 8, C = 3, H = 1024, W = 1024;
constexpr int HO = 256, WO = 256;
constexpr int HP = H + 2, WP = W + 2;
constexpr int TW = 32, TH = 16;    // output tile (w x h) per block
constexpr int IW = 160, IH = 96;   // staged input window (covers 4*tile + taps + ±16px jitter)
constexpr int LSTR = 161;          // LDS row stride (pad +1)

__device__ __forceinline__ int reflect_src(int p, int n) {
    // padded index p in [0, n+1] -> source index in [0, n-1] (numpy 'reflect')
    int s = p - 1;
    s = (s < 0) ? -s : s;
    s = (s >= n) ? (2 * n - 2 - s) : s;
    return s;
}

__global__ __launch_bounds__(256) void ds_tile(
    const float* __restrict__ img,
    const float* __restrict__ kern,
    const float* __restrict__ offh,
    const float* __restrict__ offv,
    const float* __restrict__ oup,
    float* __restrict__ out) {
    __shared__ float tile[IH * LSTR];  // 61824 B

    const int tid = threadIdx.x;
    const int tx = tid & 31;        // output w within tile
    const int ty = tid >> 5;        // 0..7; each thread does h = h0+ty and h0+ty+8
    const int w0 = blockIdx.x * TW;
    const int h0 = blockIdx.y * TH;
    const int b  = blockIdx.z;
    const int xlo = 4 * w0 - 15;    // unclamped LDS window origin (source coords)
    const int ylo = 4 * h0 - 15;
    const int w = w0 + tx;
    const float ou = oup[0];

    // Precompute sampling positions + kernel weights for all 18 (output,tap) pairs.
    float py[2][9], px[2][9], kv[2][9];
#pragma unroll
    for (int o = 0; o < 2; ++o) {
        const int h = h0 + ty + o * 8;
        const float cy = h * 4 + 1.5f;
        const float cx = w * 4 + 1.5f;
#pragma unroll
        for (int k = 0; k < 9; ++k) {
            size_t idx = (((size_t)(b * 9 + k)) * HO + h) * WO + w;
            kv[o][k] = kern[idx];
            py[o][k] = cy + (float)(k / 3) + offv[idx] * ou;
            px[o][k] = cx + (float)(k % 3) + offh[idx] * ou;
        }
    }

    float acc[2][3] = {};

    for (int c = 0; c < 3; ++c) {
        const float* __restrict__ ic = img + ((size_t)(b * 3 + c)) * (size_t)(H * W);
        __syncthreads();  // previous channel's gathers done before overwrite
        // Stage 96x160 window; slots outside the image hold clamped dupes that
        // are never read (gather sources are always in [0,H)x[0,W)).
#pragma unroll
        for (int j = 0; j < (IH * IW) / 256; ++j) {   // 60 iters
            int i = tid + j * 256;
            int ly = i / IW;
            int lx = i - ly * IW;
            int gy = min(max(ylo + ly, 0), H - 1);
            int gx = min(max(xlo + lx, 0), W - 1);
            tile[ly * LSTR + lx] = ic[gy * W + gx];
        }
        __syncthreads();

        auto fetch = [&](int sy, int sx) -> float {
            int ly = sy - ylo, lx = sx - xlo;
            if ((unsigned)ly < (unsigned)IH && (unsigned)lx < (unsigned)IW)
                return tile[ly * LSTR + lx];
            return ic[sy * W + sx];   // rare: |offset*4| beyond ±16px margin
        };

#pragma unroll
        for (int o = 0; o < 2; ++o) {
#pragma unroll
            for (int k = 0; k < 9; ++k) {
                float y0f = floorf(py[o][k]), x0f = floorf(px[o][k]);
                float bb = py[o][k] - y0f;
                float aa = px[o][k] - x0f;
                int y0 = (int)y0f, x0 = (int)x0f;
                y0 = min(max(y0, 0), HP - 1);
                x0 = min(max(x0, 0), WP - 1);
                int y1 = min(y0 + 1, HP - 1);
                int x1 = min(x0 + 1, WP - 1);
                int sy0 = reflect_src(y0, H), sy1 = reflect_src(y1, H);
                int sx0 = reflect_src(x0, W), sx1 = reflect_src(x1, W);

                float v00 = fetch(sy0, sx0);
                float v01 = fetch(sy0, sx1);
                float v10 = fetch(sy1, sx0);
                float v11 = fetch(sy1, sx1);

                float w00 = (1.f - aa) * (1.f - bb);
                float w01 = aa * (1.f - bb);
                float w10 = (1.f - aa) * bb;
                float w11 = aa * bb;
                acc[o][c] += kv[o][k] * (w00 * v00 + w01 * v01 + w10 * v10 + w11 * v11);
            }
        }
    }

#pragma unroll
    for (int o = 0; o < 2; ++o) {
        const int h = h0 + ty + o * 8;
#pragma unroll
        for (int c = 0; c < 3; ++c) {
            out[(((size_t)(b * 3 + c)) * HO + h) * WO + w] = acc[o][c];
        }
    }
}
} // namespace

extern "C" void kernel_launch(void* const* d_in, const int* in_sizes, int n_in,
                              void* d_out, int out_size, void* d_ws, size_t ws_size,
                              hipStream_t stream) {
    const float* img  = (const float*)d_in[0];
    const float* kern = (const float*)d_in[1];
    const float* offh = (const float*)d_in[2];
    const float* offv = (const float*)d_in[3];
    const float* ou   = (const float*)d_in[4];
    float* out = (float*)d_out;

    dim3 block(256);
    dim3 grid(WO / TW, HO / TH, B);   // 8 x 16 x 8 = 1024 blocks
    hipLaunchKernelGGL(ds_tile, grid, block, 0, stream,
                       img, kern, offh, offv, ou, out);
}

// Round 3
// 304.490 us; speedup vs baseline: 1.7608x; 1.7608x over previous
//
#include <hip/hip_runtime.h>
#include <cstdint>

namespace {
constexpr int B = 8, C = 3, H = 1024, W = 1024;
constexpr int HO = 256, WO = 256, K2 = 9;
constexpr int HP = H + 2, WP = W + 2;

__device__ __forceinline__ int reflect_src(int p, int n) {
    // padded index p in [0, n+1] -> source index in [0, n-1] (numpy 'reflect')
    int s = p - 1;
    s = (s < 0) ? -s : s;
    s = (s >= n) ? (2 * n - 2 - s) : s;
    return s;
}

__global__ __launch_bounds__(256) void ds_kernel(
    const float* __restrict__ img,
    const float* __restrict__ kern,
    const float* __restrict__ offh,
    const float* __restrict__ offv,
    const float* __restrict__ ou_p,
    float* __restrict__ out) {
    // XCD-aware swizzle: workgroups are assigned to XCDs round-robin
    // (XCD = blockIdx % 8). Put each batch image on ONE XCD and walk its
    // output rows contiguously, so an input row's reuse window (~9 adjacent
    // output rows x 9 taps) stays inside that XCD's private 4 MiB L2.
    int b = blockIdx.x & 7;        // XCD id
    int h = blockIdx.x >> 3;       // 0..255, contiguous in dispatch order per XCD
    int w = threadIdx.x;           // 256 threads = one output row

    const float ou = ou_p[0];
    const float cy = (h + 0.5f) * 4.0f - 0.5f;
    const float cx = (w + 0.5f) * 4.0f - 0.5f;
    const float* img0 = img + (size_t)b * (C * H * W);
    const float* img1 = img0 + H * W;
    const float* img2 = img1 + H * W;

    float acc0 = 0.f, acc1 = 0.f, acc2 = 0.f;
    size_t pbase = ((size_t)b * K2) * (size_t)(HO * WO) + (size_t)h * WO + w;

#pragma unroll
    for (int k = 0; k < K2; ++k) {
        size_t o = pbase + (size_t)(k * HO * WO);
        float kv = kern[o];
        float py = cy + (float)(k / 3) + offv[o] * ou;
        float px = cx + (float)(k % 3) + offh[o] * ou;

        float y0f = floorf(py), x0f = floorf(px);
        float bb = py - y0f;   // beta  (from unclamped floor)
        float aa = px - x0f;   // alpha (from unclamped floor)

        int y0 = (int)y0f, x0 = (int)x0f;
        y0 = min(max(y0, 0), HP - 1);
        x0 = min(max(x0, 0), WP - 1);
        int y1 = min(y0 + 1, HP - 1);   // clamp of (clamped y0)+1, per reference
        int x1 = min(x0 + 1, WP - 1);

        int sy0 = reflect_src(y0, H), sy1 = reflect_src(y1, H);
        int sx0 = reflect_src(x0, W), sx1 = reflect_src(x1, W);

        float w00 = (1.f - aa) * (1.f - bb);
        float w01 = aa * (1.f - bb);
        float w10 = (1.f - aa) * bb;
        float w11 = aa * bb;

        int i00 = sy0 * W + sx0;
        int i01 = sy0 * W + sx1;
        int i10 = sy1 * W + sx0;
        int i11 = sy1 * W + sx1;

        acc0 += kv * (w00 * img0[i00] + w01 * img0[i01] + w10 * img0[i10] + w11 * img0[i11]);
        acc1 += kv * (w00 * img1[i00] + w01 * img1[i01] + w10 * img1[i10] + w11 * img1[i11]);
        acc2 += kv * (w00 * img2[i00] + w01 * img2[i01] + w10 * img2[i10] + w11 * img2[i11]);
    }

    size_t obase = ((size_t)b * C) * (size_t)(HO * WO) + (size_t)h * WO + w;
    out[obase] = acc0;
    out[obase + (size_t)(HO * WO)] = acc1;
    out[obase + (size_t)(2 * HO * WO)] = acc2;
}
} // namespace

extern "C" void kernel_launch(void* const* d_in, const int* in_sizes, int n_in,
                              void* d_out, int out_size, void* d_ws, size_t ws_size,
                              hipStream_t stream) {
    const float* img  = (const float*)d_in[0];
    const float* kern = (const float*)d_in[1];
    const float* offh = (const float*)d_in[2];
    const float* offv = (const float*)d_in[3];
    const float* ou   = (const float*)d_in[4];
    float* out = (float*)d_out;

    dim3 block(256);
    dim3 grid(B * HO);   // 2048 blocks; one output row (b,h) each, XCD-swizzled
    hipLaunchKernelGGL(ds_kernel, grid, block, 0, stream,
                       img, kern, offh, offv, ou, out);
}